// Round 5
// baseline (259.596 us; speedup 1.0000x reference)
//
#include <hip/hip_runtime.h>
#include <cstddef>

#define BATCH 64
#define CCH   512
#define RCH   32
#define HW    1024

typedef __attribute__((ext_vector_type(8))) short short8;
typedef __attribute__((ext_vector_type(4))) float f32x4;

__device__ inline ushort f2b(float f) {   // f32 -> bf16 bits, RNE
  union { float f; uint u; } x{f};
  uint r = x.u + 0x7FFFu + ((x.u >> 16) & 1u);
  return (ushort)(r >> 16);
}
__device__ inline uint  fbits(float f) { union { float f; uint u; } x{f}; return x.u; }
__device__ inline float bitsf(uint u)  { union { uint u; float f; } x{u}; return x.f; }

// ---------------- K0: weight prep + pos repack -------------------------------
// blk<256: job0 Wcomb = Wrest@Wmask; job1..3 Wc[mix]=Wmix@Wred -> bf16 hi/lo
// blk>=256: pos fp32 [n][m] -> posr2 bf16 pairs [n][m/4] (uint2 per 4 m)
__global__ __launch_bounds__(256) void k_prep(const float* __restrict__ Wred,
    const float* __restrict__ Wrest, const float* __restrict__ Wphi,
    const float* __restrict__ Wth,   const float* __restrict__ Wg,
    const float* __restrict__ Wmask, const float* __restrict__ pos,
    float* __restrict__ Wcomb, ushort* __restrict__ Wh, ushort* __restrict__ Wl,
    uint* __restrict__ posr2) {
  const int blk = blockIdx.x;
  if (blk >= 256) {
    int id = (blk - 256) * 256 + threadIdx.x;    // 0..262143
    int n = id >> 8, m4 = id & 255;
    float4 p = *(const float4*)&pos[(size_t)n * HW + m4 * 4];
    uint2 o;
    o.x = (uint)f2b(p.x) | ((uint)f2b(p.y) << 16);
    o.y = (uint)f2b(p.z) | ((uint)f2b(p.w) << 16);
    *(uint2*)&posr2[((size_t)n * 256 + m4) * 2] = o;
    return;
  }
  int tid = blk * 256 + threadIdx.x;
  int job = tid >> 14, idx = tid & 16383;
  if (job == 0) {
    int co = idx >> 5, r = idx & 31;
    float a = 0.f;
#pragma unroll
    for (int rp = 0; rp < RCH; ++rp)
      a += Wrest[co * RCH + rp] * Wmask[rp * RCH + r];
    Wcomb[idx] = a;
  } else {
    const float* Wm = (job == 1) ? Wphi : (job == 2) ? Wth : Wg;
    int rp = idx >> 9;
    float a = 0.f;
#pragma unroll
    for (int r = 0; r < RCH; ++r)
      a += Wm[rp * RCH + r] * Wred[r * CCH + (idx & 511)];
    uint h = fbits(a) & 0xffff0000u;
    int o = (job - 1) * RCH * CCH + idx;
    Wh[o] = (ushort)(h >> 16);
    Wl[o] = f2b(a - bitsf(h));
  }
}

// ---------------- K1: phi/theta/g = Wc @ x via split-bf16 MFMA ---------------
// grid (16, 64), 256 thr = 4 waves, 16 px per wave. No LDS.
__global__ __launch_bounds__(256) void k_qkg(const float* __restrict__ x,
    const ushort* __restrict__ Wh, const ushort* __restrict__ Wl,
    const float* __restrict__ posdec,
    ushort* __restrict__ phiT, ushort* __restrict__ thT, ushort* __restrict__ g) {
  const int t = threadIdx.x;
  const int wv = t >> 6, lane = t & 63;
  const int ll = lane & 15, hl = lane >> 4;
  const int b = blockIdx.y;
  const int px0 = blockIdx.x * 64 + wv * 16;
  const f32x4 fz = {0.f, 0.f, 0.f, 0.f};

  f32x4 acc[3][2];
#pragma unroll
  for (int m1 = 0; m1 < 3; ++m1)
#pragma unroll
    for (int m2 = 0; m2 < 2; ++m2) acc[m1][m2] = fz;

  for (int kk = 0; kk < 16; ++kk) {
    const float* xp = x + ((size_t)b * CCH + kk * 32 + hl * 8) * HW + px0 + ll;
    float xv[8];
#pragma unroll
    for (int j = 0; j < 8; ++j) xv[j] = xp[(size_t)j * HW];
    short8 xh, xl;
#pragma unroll
    for (int j = 0; j < 8; ++j) {
      uint h = fbits(xv[j]) & 0xffff0000u;
      xh[j] = (short)(h >> 16);
      xl[j] = (short)f2b(xv[j] - bitsf(h));
    }
#pragma unroll
    for (int mix = 0; mix < 3; ++mix)
#pragma unroll
      for (int m = 0; m < 2; ++m) {
        const ushort* wb = Wh + (size_t)(mix * RCH + m * 16 + ll) * CCH + kk * 32 + hl * 8;
        short8 wh = *(const short8*)wb;
        short8 wl = *(const short8*)(wb + 3 * RCH * CCH);
        f32x4 a = acc[mix][m];
        a = __builtin_amdgcn_mfma_f32_16x16x32_bf16(wl, xh, a, 0, 0, 0);
        a = __builtin_amdgcn_mfma_f32_16x16x32_bf16(wh, xl, a, 0, 0, 0);
        a = __builtin_amdgcn_mfma_f32_16x16x32_bf16(wh, xh, a, 0, 0, 0);
        acc[mix][m] = a;
      }
  }

  // phi/theta: [b][px][64] hi(0..31)/lo(32..63); C/D col=ll -> px, row -> r
#pragma unroll
  for (int mix = 0; mix < 2; ++mix) {
    ushort* outb = (mix ? thT : phiT) + ((size_t)b * HW + px0) * 64;
#pragma unroll
    for (int m = 0; m < 2; ++m) {
      f32x4 v = acc[mix][m];
      uint h0 = fbits(v[0]) & 0xffff0000u, h1 = fbits(v[1]) & 0xffff0000u;
      uint h2 = fbits(v[2]) & 0xffff0000u, h3 = fbits(v[3]) & 0xffff0000u;
      uint2 hp, lp;
      hp.x = (h0 >> 16) | h1;
      hp.y = (h2 >> 16) | h3;
      lp.x = (uint)f2b(v[0] - bitsf(h0)) | ((uint)f2b(v[1] - bitsf(h1)) << 16);
      lp.y = (uint)f2b(v[2] - bitsf(h2)) | ((uint)f2b(v[3] - bitsf(h3)) << 16);
      ushort* o = outb + (size_t)ll * 64 + m * 16 + hl * 4;
      *(uint2*)o = hp;
      *(uint2*)(o + 32) = lp;
    }
  }

  // g: direct store, px = ll contiguous per lane group
#pragma unroll
  for (int m = 0; m < 2; ++m)
#pragma unroll
    for (int i = 0; i < 4; ++i) {
      int r = m * 16 + hl * 4 + i;
      float pd = posdec[(size_t)r * HW + px0 + ll];
      g[((size_t)b * RCH + r) * HW + px0 + ll] = f2b(acc[2][m][i] + pd);
    }
}

// ---------------- K2: flash attention, swapped-operand S^T -------------------
// grid (32, 64), 256 thr = 4 waves; QBLK=32 n rows; wave owns m in [wv*256,+256)
__global__ __launch_bounds__(256, 4) void k_attn(const ushort* __restrict__ phiT,
    const ushort* __restrict__ thT, const ushort* __restrict__ g,
    const uint* __restrict__ posr2, float* __restrict__ y2) {
  // union: slab ushort[4][32][72] (18432 B) <-> ypw float[4][32][36] (18432 B)
  __shared__ __align__(16) ushort slabm[4][32][72];
  __shared__ float msm[4][32], mss[4][32];
  auto ypw = (float(*)[32][36])slabm;

  const int t = threadIdx.x;
  const int wv = t >> 6, lane = t & 63;
  const int ll = lane & 15, hl = lane >> 4;
  const int b = blockIdx.y;
  const int n0 = blockIdx.x * 32;
  const f32x4 fz = {0.f, 0.f, 0.f, 0.f};

  const ushort* phib = phiT + (size_t)b * (HW * 64);
  const ushort* thb  = thT  + (size_t)b * (HW * 64);
  const ushort* gb   = g    + (size_t)b * (RCH * HW);

  // theta B-frags (persistent): col=ll -> n, k=hl*8+j -> channel
  short8 th_h[2], th_l[2];
#pragma unroll
  for (int nf = 0; nf < 2; ++nf) {
    const ushort* ap = &thb[(size_t)(n0 + nf * 16 + ll) * 64 + hl * 8];
    th_h[nf] = *(const short8*)ap;
    th_l[nf] = *(const short8*)(ap + 32);
  }

  f32x4 y[2][2] = {{fz, fz}, {fz, fz}};     // [rf][nf]; col=ll -> n, row -> r
  float m_run[2] = {-3e38f, -3e38f};
  float s_run[2] = {0.f, 0.f};

  for (int ck = 0; ck < 2; ++ck) {
    const int mch = wv * 256 + ck * 128;

    // ---- S^T = phi^T @ theta (3-term hi/lo): lane: m=mf*16+hl*4+i, n=nf*16+ll
    f32x4 acc[8][2];
#pragma unroll
    for (int mf = 0; mf < 8; ++mf) {
      const ushort* ap = &phib[(size_t)(mch + mf * 16 + ll) * 64 + hl * 8];
      short8 ph = *(const short8*)ap;
      short8 pl = *(const short8*)(ap + 32);
#pragma unroll
      for (int nf = 0; nf < 2; ++nf) {
        f32x4 a = __builtin_amdgcn_mfma_f32_16x16x32_bf16(pl, th_h[nf], fz, 0, 0, 0);
        a = __builtin_amdgcn_mfma_f32_16x16x32_bf16(ph, th_l[nf], a, 0, 0, 0);
        a = __builtin_amdgcn_mfma_f32_16x16x32_bf16(ph, th_h[nf], a, 0, 0, 0);
        acc[mf][nf] = a;
      }
    }

    // ---- + pos: lane needs pos[n][m..m+3] -> one uint2 (4 bf16) ----
#pragma unroll
    for (int nf = 0; nf < 2; ++nf) {
      const size_t nrow = (size_t)(n0 + nf * 16 + ll) * 256;
#pragma unroll
      for (int mf = 0; mf < 8; ++mf) {
        uint2 pp = *(const uint2*)&posr2[(nrow + (mch >> 2) + mf * 4 + hl) * 2];
        acc[mf][nf][0] += bitsf(pp.x << 16);
        acc[mf][nf][1] += bitsf(pp.x & 0xffff0000u);
        acc[mf][nf][2] += bitsf(pp.y << 16);
        acc[mf][nf][3] += bitsf(pp.y & 0xffff0000u);
      }
    }

    // ---- online softmax over chunk (row n = nf*16+ll, reduce over hl) ----
#pragma unroll
    for (int nf = 0; nf < 2; ++nf) {
      float mv = acc[0][nf][0];
#pragma unroll
      for (int mf = 0; mf < 8; ++mf)
#pragma unroll
        for (int i = 0; i < 4; ++i) mv = fmaxf(mv, acc[mf][nf][i]);
      mv = fmaxf(mv, __shfl_xor(mv, 16));
      mv = fmaxf(mv, __shfl_xor(mv, 32));
      float mnew = fmaxf(m_run[nf], mv);
      float fac = __expf(m_run[nf] - mnew);
      m_run[nf] = mnew;
      float s_ = 0.f;
#pragma unroll
      for (int mf = 0; mf < 8; ++mf)
#pragma unroll
        for (int i = 0; i < 4; ++i) {
          float p = __expf(acc[mf][nf][i] - mnew);
          acc[mf][nf][i] = p;
          s_ += p;
        }
      s_ += __shfl_xor(s_, 16);
      s_ += __shfl_xor(s_, 32);
      s_run[nf] = s_run[nf] * fac + s_;
#pragma unroll
      for (int rf = 0; rf < 2; ++rf) y[rf][nf] *= fac;
    }

    // ---- PV in two 64-m halves through per-wave slab ----
#pragma unroll
    for (int h = 0; h < 2; ++h) {
#pragma unroll
      for (int mf2 = 0; mf2 < 4; ++mf2)
#pragma unroll
        for (int nf = 0; nf < 2; ++nf) {
          f32x4 v = acc[h * 4 + mf2][nf];
          uint2 w;
          w.x = (uint)f2b(v[0]) | ((uint)f2b(v[1]) << 16);
          w.y = (uint)f2b(v[2]) | ((uint)f2b(v[3]) << 16);
          *(uint2*)&slabm[wv][nf * 16 + ll][mf2 * 16 + hl * 4] = w;
        }
      asm volatile("s_waitcnt lgkmcnt(0)" ::: "memory");
      __builtin_amdgcn_sched_barrier(0);
#pragma unroll
      for (int ks = 0; ks < 2; ++ks) {
        short8 bfr[2];
#pragma unroll
        for (int nblk = 0; nblk < 2; ++nblk)
          bfr[nblk] = *(const short8*)&slabm[wv][nblk * 16 + ll][ks * 32 + hl * 8];
#pragma unroll
        for (int rf = 0; rf < 2; ++rf) {
          short8 ag = *(const short8*)&gb[(size_t)(rf * 16 + ll) * HW + mch + h * 64 + ks * 32 + hl * 8];
#pragma unroll
          for (int nblk = 0; nblk < 2; ++nblk)
            y[rf][nblk] = __builtin_amdgcn_mfma_f32_16x16x32_bf16(ag, bfr[nblk], y[rf][nblk], 0, 0, 0);
        }
      }
      asm volatile("s_waitcnt lgkmcnt(0)" ::: "memory");
      __builtin_amdgcn_sched_barrier(0);
    }
  }

  // ---- all waves done with slab; write partials into union'd ypw ----
  __syncthreads();
#pragma unroll
  for (int rf = 0; rf < 2; ++rf)
#pragma unroll
    for (int nblk = 0; nblk < 2; ++nblk)
      *(f32x4*)&ypw[wv][nblk * 16 + ll][rf * 16 + hl * 4] = y[rf][nblk];
  if (hl == 0) {
    msm[wv][ll] = m_run[0];
    mss[wv][ll] = s_run[0];
    msm[wv][16 + ll] = m_run[1];
    mss[wv][16 + ll] = s_run[1];
  }
  __syncthreads();

  // ---- merge 4 wave-partials, normalize, store ----
  {
    const int n = t & 31, rr = t >> 5;
    float M = msm[0][n];
#pragma unroll
    for (int w = 1; w < 4; ++w) M = fmaxf(M, msm[w][n]);
    float sc[4];
    float s = 0.f;
#pragma unroll
    for (int w = 0; w < 4; ++w) {
      sc[w] = __expf(msm[w][n] - M);
      s += mss[w][n] * sc[w];
    }
    float inv = 1.f / s;
    f32x4 a = sc[0] * (*(const f32x4*)&ypw[0][n][rr * 4]);
#pragma unroll
    for (int w = 1; w < 4; ++w) a += sc[w] * (*(const f32x4*)&ypw[w][n][rr * 4]);
#pragma unroll
    for (int k = 0; k < 4; ++k)
      y2[((size_t)b * RCH + rr * 4 + k) * HW + n0 + n] = a[k] * inv;
  }
}

// ---------------- K3: out = x + Wcomb @ y2 (co split over grid.y) ------------
__global__ __launch_bounds__(256) void k_restore(const float* __restrict__ x,
    const float* __restrict__ Wcomb, const float* __restrict__ y2,
    float* __restrict__ out) {
  const int t = threadIdx.x;
  const int gp = blockIdx.x * 256 + t;
  const int b = gp >> 10, n = gp & 1023;
  const int co0 = blockIdx.y * 64;

  float yv[RCH];
  const float* y2b = y2 + ((size_t)b * RCH) * HW + n;
#pragma unroll
  for (int r = 0; r < RCH; ++r) yv[r] = y2b[(size_t)r * HW];

  const float* xb = x + ((size_t)b * CCH) * HW + n;
  float* ob = out + ((size_t)b * CCH) * HW + n;
  for (int co = co0; co < co0 + 64; ++co) {
    float a = xb[(size_t)co * HW];
#pragma unroll
    for (int qq = 0; qq < RCH; qq += 4) {
      const float4 w = *(const float4*)(Wcomb + co * RCH + qq);
      a += w.x * yv[qq] + w.y * yv[qq + 1] + w.z * yv[qq + 2] + w.w * yv[qq + 3];
    }
    ob[(size_t)co * HW] = a;
  }
}

extern "C" void kernel_launch(void* const* d_in, const int* in_sizes, int n_in,
                              void* d_out, int out_size, void* d_ws, size_t ws_size,
                              hipStream_t stream) {
  const float* x      = (const float*)d_in[0];
  const float* Wred   = (const float*)d_in[1];
  const float* Wrest  = (const float*)d_in[2];
  const float* Wphi   = (const float*)d_in[3];
  const float* Wth    = (const float*)d_in[4];
  const float* Wg     = (const float*)d_in[5];
  const float* Wmask  = (const float*)d_in[6];
  const float* pos    = (const float*)d_in[7];
  const float* posdec = (const float*)d_in[8];
  float* out = (float*)d_out;

  const size_t PT = (size_t)BATCH * HW * 64;     // phiT/thT shorts (hi+lo)
  const size_t NE = (size_t)BATCH * RCH * HW;    // 2M
  ushort* phiT = (ushort*)d_ws;
  ushort* thT  = phiT + PT;
  ushort* gbuf = thT + PT;
  float*  y2   = (float*)(gbuf + NE);
  float*  Wcomb = y2 + NE;
  ushort* Wh   = (ushort*)(Wcomb + CCH * RCH);
  ushort* Wl   = Wh + 3 * RCH * CCH;
  uint*   posr2 = (uint*)(Wl + 3 * RCH * CCH);   // 512K uints (2 MB)

  k_prep   <<<dim3(1280),    dim3(256), 0, stream>>>(Wred, Wrest, Wphi, Wth, Wg, Wmask,
                                                     pos, Wcomb, Wh, Wl, posr2);
  k_qkg    <<<dim3(16, 64),  dim3(256), 0, stream>>>(x, Wh, Wl, posdec, phiT, thT, gbuf);
  k_attn   <<<dim3(32, 64),  dim3(256), 0, stream>>>(phiT, thT, gbuf, posr2, y2);
  k_restore<<<dim3(256, 8),  dim3(256), 0, stream>>>(x, Wcomb, y2, out);
}

// Round 6
// 226.634 us; speedup vs baseline: 1.1454x; 1.1454x over previous
//
#include <hip/hip_runtime.h>
#include <cstddef>

#define BATCH 64
#define CCH   512
#define RCH   32
#define HW    1024

typedef __attribute__((ext_vector_type(8))) short short8;
typedef __attribute__((ext_vector_type(4))) float f32x4;

__device__ inline ushort f2b(float f) {   // f32 -> bf16 bits, RNE
  union { float f; uint u; } x{f};
  uint r = x.u + 0x7FFFu + ((x.u >> 16) & 1u);
  return (ushort)(r >> 16);
}
__device__ inline uint  fbits(float f) { union { float f; uint u; } x{f}; return x.u; }
__device__ inline float bitsf(uint u)  { union { uint u; float f; } x{u}; return x.f; }

__device__ inline void gload4(const float* g, float* lds) {
  __builtin_amdgcn_global_load_lds((const __attribute__((address_space(1))) void*)g,
                                   (__attribute__((address_space(3))) void*)lds, 4, 0, 0);
}

// ---------------- K0: weight prep + pos repack -------------------------------
// blk<256: job0 Wcomb = Wrest@Wmask; job1..3 Wc[mix]=Wmix@Wred -> bf16 hi/lo
// blk 256..511: pos fp32 [n][m] -> posq[m4][n] uint2 (4 consecutive-m bf16)
__global__ __launch_bounds__(256) void k_prep(const float* __restrict__ Wred,
    const float* __restrict__ Wrest, const float* __restrict__ Wphi,
    const float* __restrict__ Wth,   const float* __restrict__ Wg,
    const float* __restrict__ Wmask, const float* __restrict__ pos,
    float* __restrict__ Wcomb, ushort* __restrict__ Wh, ushort* __restrict__ Wl,
    uint2* __restrict__ posq) {
  const int blk = blockIdx.x;
  const int t = threadIdx.x;
  if (blk >= 256) {
    __shared__ ushort tile[64][68];
    int tb = blk - 256;
    int n0 = (tb >> 4) * 64, m0 = (tb & 15) * 64;
    int nl = t >> 2, c4 = t & 3;
    const float* src = &pos[(size_t)(n0 + nl) * HW + m0 + c4 * 16];
#pragma unroll
    for (int k = 0; k < 4; ++k) {
      float4 p = *(const float4*)(src + k * 4);
      ushort* d = &tile[nl][c4 * 16 + k * 4];
      d[0] = f2b(p.x); d[1] = f2b(p.y); d[2] = f2b(p.z); d[3] = f2b(p.w);
    }
    __syncthreads();
    int nl2 = t & 63, mq = t >> 6;
#pragma unroll
    for (int k = 0; k < 4; ++k) {
      int m4l = k * 4 + mq;
      const ushort* s = &tile[nl2][m4l * 4];
      uint2 o;
      o.x = (uint)s[0] | ((uint)s[1] << 16);
      o.y = (uint)s[2] | ((uint)s[3] << 16);
      posq[(size_t)(m0 / 4 + m4l) * HW + n0 + nl2] = o;
    }
    return;
  }
  int tid = blk * 256 + t;
  int job = tid >> 14, idx = tid & 16383;
  if (job == 0) {
    int co = idx >> 5, r = idx & 31;
    float a = 0.f;
#pragma unroll
    for (int rp = 0; rp < RCH; ++rp)
      a += Wrest[co * RCH + rp] * Wmask[rp * RCH + r];
    Wcomb[idx] = a;
  } else {
    const float* Wm = (job == 1) ? Wphi : (job == 2) ? Wth : Wg;
    int rp = idx >> 9;
    float a = 0.f;
#pragma unroll
    for (int r = 0; r < RCH; ++r)
      a += Wm[rp * RCH + r] * Wred[r * CCH + (idx & 511)];
    uint h = fbits(a) & 0xffff0000u;
    int o = (job - 1) * RCH * CCH + idx;
    Wh[o] = (ushort)(h >> 16);
    Wl[o] = f2b(a - bitsf(h));
  }
}

// ---------------- K1: phi/theta/g = Wc @ x, LDS-staged x ---------------------
// grid (8, 64), 256 thr = 4 waves, wave = 32 px. x staged 32ch x 128px per kk.
__global__ __launch_bounds__(256) void k_qkg(const float* __restrict__ x,
    const ushort* __restrict__ Wh, const ushort* __restrict__ Wl,
    const float* __restrict__ posdec,
    ushort* __restrict__ phiT, ushort* __restrict__ thT, ushort* __restrict__ g) {
  __shared__ float buf[2][32][129];      // 33 KB double-buffered x tile
  auto gt = (float(*)[32][33])buf;       // overlay for g epilogue

  const int t = threadIdx.x;
  const int wv = t >> 6, lane = t & 63;
  const int ll = lane & 15, hl = lane >> 4;
  const int b = blockIdx.y;
  const int px0b = blockIdx.x * 128;
  const int px0 = px0b + wv * 32;
  const f32x4 fz = {0.f, 0.f, 0.f, 0.f};

  f32x4 acc[3][2][2];
#pragma unroll
  for (int m1 = 0; m1 < 3; ++m1)
#pragma unroll
    for (int m2 = 0; m2 < 2; ++m2)
#pragma unroll
      for (int m3 = 0; m3 < 2; ++m3) acc[m1][m2][m3] = fz;

  // stage kk=0
  {
    const float* xbase = x + ((size_t)b * CCH) * HW + px0b;
#pragma unroll
    for (int i2 = 0; i2 < 16; ++i2) {
      int idx = wv * 16 + i2, ch = idx >> 1, hf = idx & 1;
      gload4(xbase + (size_t)ch * HW + hf * 64 + lane, &buf[0][ch][hf * 64]);
    }
  }
  __syncthreads();

  for (int kk = 0; kk < 16; ++kk) {
    const int cur = kk & 1;
    if (kk < 15) {
      const float* xbase = x + ((size_t)b * CCH + (kk + 1) * 32) * HW + px0b;
#pragma unroll
      for (int i2 = 0; i2 < 16; ++i2) {
        int idx = wv * 16 + i2, ch = idx >> 1, hf = idx & 1;
        gload4(xbase + (size_t)ch * HW + hf * 64 + lane, &buf[cur ^ 1][ch][hf * 64]);
      }
    }
    // frags from LDS + hi/lo split
    short8 xh[2], xl[2];
#pragma unroll
    for (int pf = 0; pf < 2; ++pf) {
      float xv[8];
#pragma unroll
      for (int j = 0; j < 8; ++j) xv[j] = buf[cur][hl * 8 + j][wv * 32 + pf * 16 + ll];
#pragma unroll
      for (int j = 0; j < 8; ++j) {
        uint h = fbits(xv[j]) & 0xffff0000u;
        xh[pf][j] = (short)(h >> 16);
        xl[pf][j] = (short)f2b(xv[j] - bitsf(h));
      }
    }
#pragma unroll
    for (int mix = 0; mix < 3; ++mix)
#pragma unroll
      for (int m = 0; m < 2; ++m) {
        const ushort* wb = Wh + (size_t)(mix * RCH + m * 16 + ll) * CCH + kk * 32 + hl * 8;
        short8 wh = *(const short8*)wb;
        short8 wl = *(const short8*)(wb + 3 * RCH * CCH);
#pragma unroll
        for (int pf = 0; pf < 2; ++pf) {
          f32x4 a = acc[mix][m][pf];
          a = __builtin_amdgcn_mfma_f32_16x16x32_bf16(wl, xh[pf], a, 0, 0, 0);
          a = __builtin_amdgcn_mfma_f32_16x16x32_bf16(wh, xl[pf], a, 0, 0, 0);
          a = __builtin_amdgcn_mfma_f32_16x16x32_bf16(wh, xh[pf], a, 0, 0, 0);
          acc[mix][m][pf] = a;
        }
      }
    __syncthreads();   // drain stage loads for kk+1; protect WAR for kk+2
  }

  // phi/theta: [b][px][64] hi(0..31)/lo(32..63)
#pragma unroll
  for (int mix = 0; mix < 2; ++mix) {
    ushort* outb = (mix ? thT : phiT) + ((size_t)b * HW + px0) * 64;
#pragma unroll
    for (int m = 0; m < 2; ++m)
#pragma unroll
      for (int pf = 0; pf < 2; ++pf) {
        f32x4 v = acc[mix][m][pf];
        uint h0 = fbits(v[0]) & 0xffff0000u, h1 = fbits(v[1]) & 0xffff0000u;
        uint h2 = fbits(v[2]) & 0xffff0000u, h3 = fbits(v[3]) & 0xffff0000u;
        uint2 hp, lp;
        hp.x = (h0 >> 16) | h1;
        hp.y = (h2 >> 16) | h3;
        lp.x = (uint)f2b(v[0] - bitsf(h0)) | ((uint)f2b(v[1] - bitsf(h1)) << 16);
        lp.y = (uint)f2b(v[2] - bitsf(h2)) | ((uint)f2b(v[3] - bitsf(h3)) << 16);
        ushort* o = outb + (size_t)(pf * 16 + ll) * 64 + m * 16 + hl * 4;
        *(uint2*)o = hp;
        *(uint2*)(o + 32) = lp;
      }
  }

  // g epilogue via LDS transpose (reuses buf)
  __syncthreads();
#pragma unroll
  for (int m = 0; m < 2; ++m)
#pragma unroll
    for (int pf = 0; pf < 2; ++pf)
#pragma unroll
      for (int i = 0; i < 4; ++i)
        gt[wv][m * 16 + hl * 4 + i][pf * 16 + ll] = acc[2][m][pf][i];
  __syncthreads();
#pragma unroll
  for (int rr = 0; rr < 8; ++rr) {
    int r = rr * 4 + hl, p2 = ll * 2;
    float a = gt[wv][r][p2], bv = gt[wv][r][p2 + 1];
    const float2 pd = *(const float2*)&posdec[(size_t)r * HW + px0 + p2];
    uint pk = (uint)f2b(a + pd.x) | ((uint)f2b(bv + pd.y) << 16);
    *(uint*)(g + ((size_t)b * RCH + r) * HW + px0 + p2) = pk;
  }
}

// ---------------- K2: flash attention, swapped-operand S^T -------------------
// grid (32, 64), 256 thr = 4 waves; QBLK=32 n rows; wave owns m in [wv*256,+256)
__global__ __launch_bounds__(256, 4) void k_attn(const ushort* __restrict__ phiT,
    const ushort* __restrict__ thT, const ushort* __restrict__ g,
    const uint2* __restrict__ posq, float* __restrict__ y2) {
  __shared__ __align__(16) ushort slabm[4][32][72];
  __shared__ float msm[4][32], mss[4][32];
  auto ypw = (float(*)[32][36])slabm;

  const int t = threadIdx.x;
  const int wv = t >> 6, lane = t & 63;
  const int ll = lane & 15, hl = lane >> 4;
  const int b = blockIdx.y;
  const int n0 = blockIdx.x * 32;
  const f32x4 fz = {0.f, 0.f, 0.f, 0.f};

  const ushort* phib = phiT + (size_t)b * (HW * 64);
  const ushort* thb  = thT  + (size_t)b * (HW * 64);
  const ushort* gb   = g    + (size_t)b * (RCH * HW);

  short8 th_h[2], th_l[2];
#pragma unroll
  for (int nf = 0; nf < 2; ++nf) {
    const ushort* ap = &thb[(size_t)(n0 + nf * 16 + ll) * 64 + hl * 8];
    th_h[nf] = *(const short8*)ap;
    th_l[nf] = *(const short8*)(ap + 32);
  }

  f32x4 y[2][2] = {{fz, fz}, {fz, fz}};
  float m_run[2] = {-3e38f, -3e38f};
  float s_run[2] = {0.f, 0.f};

  for (int ck = 0; ck < 2; ++ck) {
    const int mch = wv * 256 + ck * 128;

    // S^T = phi^T @ theta: lane: m = mf*16+hl*4+i, n = nf*16+ll
    f32x4 acc[8][2];
#pragma unroll
    for (int mf = 0; mf < 8; ++mf) {
      const ushort* ap = &phib[(size_t)(mch + mf * 16 + ll) * 64 + hl * 8];
      short8 ph = *(const short8*)ap;
      short8 pl = *(const short8*)(ap + 32);
#pragma unroll
      for (int nf = 0; nf < 2; ++nf) {
        f32x4 a = __builtin_amdgcn_mfma_f32_16x16x32_bf16(pl, th_h[nf], fz, 0, 0, 0);
        a = __builtin_amdgcn_mfma_f32_16x16x32_bf16(ph, th_l[nf], a, 0, 0, 0);
        a = __builtin_amdgcn_mfma_f32_16x16x32_bf16(ph, th_h[nf], a, 0, 0, 0);
        acc[mf][nf] = a;
      }
    }

    // + pos from posq[m4][n]: lanes vary ll -> n consecutive (coalesced)
#pragma unroll
    for (int nf = 0; nf < 2; ++nf) {
      const int nidx = n0 + nf * 16 + ll;
#pragma unroll
      for (int mf = 0; mf < 8; ++mf) {
        uint2 pp = posq[(size_t)((mch >> 2) + mf * 4 + hl) * HW + nidx];
        acc[mf][nf][0] += bitsf(pp.x << 16);
        acc[mf][nf][1] += bitsf(pp.x & 0xffff0000u);
        acc[mf][nf][2] += bitsf(pp.y << 16);
        acc[mf][nf][3] += bitsf(pp.y & 0xffff0000u);
      }
    }

    // online softmax over chunk (row n = nf*16+ll, reduce over hl)
#pragma unroll
    for (int nf = 0; nf < 2; ++nf) {
      float mv = acc[0][nf][0];
#pragma unroll
      for (int mf = 0; mf < 8; ++mf)
#pragma unroll
        for (int i = 0; i < 4; ++i) mv = fmaxf(mv, acc[mf][nf][i]);
      mv = fmaxf(mv, __shfl_xor(mv, 16));
      mv = fmaxf(mv, __shfl_xor(mv, 32));
      float mnew = fmaxf(m_run[nf], mv);
      float fac = __expf(m_run[nf] - mnew);
      m_run[nf] = mnew;
      float s_ = 0.f;
#pragma unroll
      for (int mf = 0; mf < 8; ++mf)
#pragma unroll
        for (int i = 0; i < 4; ++i) {
          float p = __expf(acc[mf][nf][i] - mnew);
          acc[mf][nf][i] = p;
          s_ += p;
        }
      s_ += __shfl_xor(s_, 16);
      s_ += __shfl_xor(s_, 32);
      s_run[nf] = s_run[nf] * fac + s_;
#pragma unroll
      for (int rf = 0; rf < 2; ++rf) y[rf][nf] *= fac;
    }

    // PV in two 64-m halves through per-wave slab
#pragma unroll
    for (int h = 0; h < 2; ++h) {
#pragma unroll
      for (int mf2 = 0; mf2 < 4; ++mf2)
#pragma unroll
        for (int nf = 0; nf < 2; ++nf) {
          f32x4 v = acc[h * 4 + mf2][nf];
          uint2 w;
          w.x = (uint)f2b(v[0]) | ((uint)f2b(v[1]) << 16);
          w.y = (uint)f2b(v[2]) | ((uint)f2b(v[3]) << 16);
          *(uint2*)&slabm[wv][nf * 16 + ll][mf2 * 16 + hl * 4] = w;
        }
      asm volatile("s_waitcnt lgkmcnt(0)" ::: "memory");
      __builtin_amdgcn_sched_barrier(0);
#pragma unroll
      for (int ks = 0; ks < 2; ++ks) {
        short8 bfr[2];
#pragma unroll
        for (int nblk = 0; nblk < 2; ++nblk)
          bfr[nblk] = *(const short8*)&slabm[wv][nblk * 16 + ll][ks * 32 + hl * 8];
#pragma unroll
        for (int rf = 0; rf < 2; ++rf) {
          short8 ag = *(const short8*)&gb[(size_t)(rf * 16 + ll) * HW + mch + h * 64 + ks * 32 + hl * 8];
#pragma unroll
          for (int nblk = 0; nblk < 2; ++nblk)
            y[rf][nblk] = __builtin_amdgcn_mfma_f32_16x16x32_bf16(ag, bfr[nblk], y[rf][nblk], 0, 0, 0);
        }
      }
      asm volatile("s_waitcnt lgkmcnt(0)" ::: "memory");
      __builtin_amdgcn_sched_barrier(0);
    }
  }

  __syncthreads();
#pragma unroll
  for (int rf = 0; rf < 2; ++rf)
#pragma unroll
    for (int nblk = 0; nblk < 2; ++nblk)
      *(f32x4*)&ypw[wv][nblk * 16 + ll][rf * 16 + hl * 4] = y[rf][nblk];
  if (hl == 0) {
    msm[wv][ll] = m_run[0];
    mss[wv][ll] = s_run[0];
    msm[wv][16 + ll] = m_run[1];
    mss[wv][16 + ll] = s_run[1];
  }
  __syncthreads();

  {
    const int n = t & 31, rr = t >> 5;
    float M = msm[0][n];
#pragma unroll
    for (int w = 1; w < 4; ++w) M = fmaxf(M, msm[w][n]);
    float sc[4];
    float s = 0.f;
#pragma unroll
    for (int w = 0; w < 4; ++w) {
      sc[w] = __expf(msm[w][n] - M);
      s += mss[w][n] * sc[w];
    }
    float inv = 1.f / s;
    f32x4 a = sc[0] * (*(const f32x4*)&ypw[0][n][rr * 4]);
#pragma unroll
    for (int w = 1; w < 4; ++w) a += sc[w] * (*(const f32x4*)&ypw[w][n][rr * 4]);
#pragma unroll
    for (int k = 0; k < 4; ++k)
      y2[((size_t)b * RCH + rr * 4 + k) * HW + n0 + n] = a[k] * inv;
  }
}

// ---------------- K3: out = x + Wcomb @ y2 (co split over grid.y) ------------
__global__ __launch_bounds__(256) void k_restore(const float* __restrict__ x,
    const float* __restrict__ Wcomb, const float* __restrict__ y2,
    float* __restrict__ out) {
  const int t = threadIdx.x;
  const int gp = blockIdx.x * 256 + t;
  const int b = gp >> 10, n = gp & 1023;
  const int co0 = blockIdx.y * 64;

  float yv[RCH];
  const float* y2b = y2 + ((size_t)b * RCH) * HW + n;
#pragma unroll
  for (int r = 0; r < RCH; ++r) yv[r] = y2b[(size_t)r * HW];

  const float* xb = x + ((size_t)b * CCH) * HW + n;
  float* ob = out + ((size_t)b * CCH) * HW + n;
  for (int co = co0; co < co0 + 64; ++co) {
    float a = xb[(size_t)co * HW];
#pragma unroll
    for (int qq = 0; qq < RCH; qq += 4) {
      const float4 w = *(const float4*)(Wcomb + co * RCH + qq);
      a += w.x * yv[qq] + w.y * yv[qq + 1] + w.z * yv[qq + 2] + w.w * yv[qq + 3];
    }
    ob[(size_t)co * HW] = a;
  }
}

extern "C" void kernel_launch(void* const* d_in, const int* in_sizes, int n_in,
                              void* d_out, int out_size, void* d_ws, size_t ws_size,
                              hipStream_t stream) {
  const float* x      = (const float*)d_in[0];
  const float* Wred   = (const float*)d_in[1];
  const float* Wrest  = (const float*)d_in[2];
  const float* Wphi   = (const float*)d_in[3];
  const float* Wth    = (const float*)d_in[4];
  const float* Wg     = (const float*)d_in[5];
  const float* Wmask  = (const float*)d_in[6];
  const float* pos    = (const float*)d_in[7];
  const float* posdec = (const float*)d_in[8];
  float* out = (float*)d_out;

  const size_t PT = (size_t)BATCH * HW * 64;     // phiT/thT shorts (hi+lo)
  const size_t NE = (size_t)BATCH * RCH * HW;    // 2M
  ushort* phiT = (ushort*)d_ws;
  ushort* thT  = phiT + PT;
  ushort* gbuf = thT + PT;
  float*  y2   = (float*)(gbuf + NE);
  float*  Wcomb = y2 + NE;
  ushort* Wh   = (ushort*)(Wcomb + CCH * RCH);
  ushort* Wl   = Wh + 3 * RCH * CCH;
  uint2*  posq = (uint2*)(Wl + 3 * RCH * CCH);   // 256K uint2 (2 MB)

  k_prep   <<<dim3(512),     dim3(256), 0, stream>>>(Wred, Wrest, Wphi, Wth, Wg, Wmask,
                                                     pos, Wcomb, Wh, Wl, posq);
  k_qkg    <<<dim3(8, 64),   dim3(256), 0, stream>>>(x, Wh, Wl, posdec, phiT, thT, gbuf);
  k_attn   <<<dim3(32, 64),  dim3(256), 0, stream>>>(phiT, thT, gbuf, posq, y2);
  k_restore<<<dim3(256, 8),  dim3(256), 0, stream>>>(x, Wcomb, y2, out);
}

// Round 7
// 202.634 us; speedup vs baseline: 1.2811x; 1.1184x over previous
//
#include <hip/hip_runtime.h>
#include <cstddef>

#define BATCH 64
#define CCH   512
#define RCH   32
#define HW    1024

typedef __attribute__((ext_vector_type(8))) short short8;
typedef __attribute__((ext_vector_type(4))) float f32x4;

__device__ inline ushort f2b(float f) {   // f32 -> bf16 bits, RNE
  union { float f; uint u; } x{f};
  uint r = x.u + 0x7FFFu + ((x.u >> 16) & 1u);
  return (ushort)(r >> 16);
}
__device__ inline uint  fbits(float f) { union { float f; uint u; } x{f}; return x.u; }
__device__ inline float bitsf(uint u)  { union { uint u; float f; } x{u}; return x.f; }

__device__ inline void gload4(const float* g, float* lds) {
  __builtin_amdgcn_global_load_lds((const __attribute__((address_space(1))) void*)g,
                                   (__attribute__((address_space(3))) void*)lds, 4, 0, 0);
}

// ---------------- K0: weight prep + pos repack -------------------------------
__global__ __launch_bounds__(256) void k_prep(const float* __restrict__ Wred,
    const float* __restrict__ Wrest, const float* __restrict__ Wphi,
    const float* __restrict__ Wth,   const float* __restrict__ Wg,
    const float* __restrict__ Wmask, const float* __restrict__ pos,
    float* __restrict__ Wcomb, ushort* __restrict__ Wh, ushort* __restrict__ Wl,
    uint2* __restrict__ posq) {
  const int blk = blockIdx.x;
  const int t = threadIdx.x;
  if (blk >= 256) {
    __shared__ ushort tile[64][68];
    int tb = blk - 256;
    int n0 = (tb >> 4) * 64, m0 = (tb & 15) * 64;
    int nl = t >> 2, c4 = t & 3;
    const float* src = &pos[(size_t)(n0 + nl) * HW + m0 + c4 * 16];
#pragma unroll
    for (int k = 0; k < 4; ++k) {
      float4 p = *(const float4*)(src + k * 4);
      ushort* d = &tile[nl][c4 * 16 + k * 4];
      d[0] = f2b(p.x); d[1] = f2b(p.y); d[2] = f2b(p.z); d[3] = f2b(p.w);
    }
    __syncthreads();
    int nl2 = t & 63, mq = t >> 6;
#pragma unroll
    for (int k = 0; k < 4; ++k) {
      int m4l = k * 4 + mq;
      const ushort* s = &tile[nl2][m4l * 4];
      uint2 o;
      o.x = (uint)s[0] | ((uint)s[1] << 16);
      o.y = (uint)s[2] | ((uint)s[3] << 16);
      posq[(size_t)(m0 / 4 + m4l) * HW + n0 + nl2] = o;
    }
    return;
  }
  int tid = blk * 256 + t;
  int job = tid >> 14, idx = tid & 16383;
  if (job == 0) {
    int co = idx >> 5, r = idx & 31;
    float a = 0.f;
#pragma unroll
    for (int rp = 0; rp < RCH; ++rp)
      a += Wrest[co * RCH + rp] * Wmask[rp * RCH + r];
    Wcomb[idx] = a;
  } else {
    const float* Wm = (job == 1) ? Wphi : (job == 2) ? Wth : Wg;
    int rp = idx >> 9;
    float a = 0.f;
#pragma unroll
    for (int r = 0; r < RCH; ++r)
      a += Wm[rp * RCH + r] * Wred[r * CCH + (idx & 511)];
    uint h = fbits(a) & 0xffff0000u;
    int o = (job - 1) * RCH * CCH + idx;
    Wh[o] = (ushort)(h >> 16);
    Wl[o] = f2b(a - bitsf(h));
  }
}

// ---------------- K1: phi/theta/g = Wc @ x, LDS-staged x ---------------------
__global__ __launch_bounds__(256) void k_qkg(const float* __restrict__ x,
    const ushort* __restrict__ Wh, const ushort* __restrict__ Wl,
    const float* __restrict__ posdec,
    ushort* __restrict__ phiT, ushort* __restrict__ thT, ushort* __restrict__ g) {
  __shared__ float buf[2][32][129];      // 33 KB double-buffered x tile
  auto gt = (float(*)[32][33])buf;       // overlay for g epilogue

  const int t = threadIdx.x;
  const int wv = t >> 6, lane = t & 63;
  const int ll = lane & 15, hl = lane >> 4;
  const int b = blockIdx.y;
  const int px0b = blockIdx.x * 128;
  const int px0 = px0b + wv * 32;
  const f32x4 fz = {0.f, 0.f, 0.f, 0.f};

  f32x4 acc[3][2][2];
#pragma unroll
  for (int m1 = 0; m1 < 3; ++m1)
#pragma unroll
    for (int m2 = 0; m2 < 2; ++m2)
#pragma unroll
      for (int m3 = 0; m3 < 2; ++m3) acc[m1][m2][m3] = fz;

  {
    const float* xbase = x + ((size_t)b * CCH) * HW + px0b;
#pragma unroll
    for (int i2 = 0; i2 < 16; ++i2) {
      int idx = wv * 16 + i2, ch = idx >> 1, hf = idx & 1;
      gload4(xbase + (size_t)ch * HW + hf * 64 + lane, &buf[0][ch][hf * 64]);
    }
  }
  __syncthreads();

  for (int kk = 0; kk < 16; ++kk) {
    const int cur = kk & 1;
    if (kk < 15) {
      const float* xbase = x + ((size_t)b * CCH + (kk + 1) * 32) * HW + px0b;
#pragma unroll
      for (int i2 = 0; i2 < 16; ++i2) {
        int idx = wv * 16 + i2, ch = idx >> 1, hf = idx & 1;
        gload4(xbase + (size_t)ch * HW + hf * 64 + lane, &buf[cur ^ 1][ch][hf * 64]);
      }
    }
    short8 xh[2], xl[2];
#pragma unroll
    for (int pf = 0; pf < 2; ++pf) {
      float xv[8];
#pragma unroll
      for (int j = 0; j < 8; ++j) xv[j] = buf[cur][hl * 8 + j][wv * 32 + pf * 16 + ll];
#pragma unroll
      for (int j = 0; j < 8; ++j) {
        uint h = fbits(xv[j]) & 0xffff0000u;
        xh[pf][j] = (short)(h >> 16);
        xl[pf][j] = (short)f2b(xv[j] - bitsf(h));
      }
    }
#pragma unroll
    for (int mix = 0; mix < 3; ++mix)
#pragma unroll
      for (int m = 0; m < 2; ++m) {
        const ushort* wb = Wh + (size_t)(mix * RCH + m * 16 + ll) * CCH + kk * 32 + hl * 8;
        short8 wh = *(const short8*)wb;
        short8 wl = *(const short8*)(wb + 3 * RCH * CCH);
#pragma unroll
        for (int pf = 0; pf < 2; ++pf) {
          f32x4 a = acc[mix][m][pf];
          a = __builtin_amdgcn_mfma_f32_16x16x32_bf16(wl, xh[pf], a, 0, 0, 0);
          a = __builtin_amdgcn_mfma_f32_16x16x32_bf16(wh, xl[pf], a, 0, 0, 0);
          a = __builtin_amdgcn_mfma_f32_16x16x32_bf16(wh, xh[pf], a, 0, 0, 0);
          acc[mix][m][pf] = a;
        }
      }
    __syncthreads();
  }

#pragma unroll
  for (int mix = 0; mix < 2; ++mix) {
    ushort* outb = (mix ? thT : phiT) + ((size_t)b * HW + px0) * 64;
#pragma unroll
    for (int m = 0; m < 2; ++m)
#pragma unroll
      for (int pf = 0; pf < 2; ++pf) {
        f32x4 v = acc[mix][m][pf];
        uint h0 = fbits(v[0]) & 0xffff0000u, h1 = fbits(v[1]) & 0xffff0000u;
        uint h2 = fbits(v[2]) & 0xffff0000u, h3 = fbits(v[3]) & 0xffff0000u;
        uint2 hp, lp;
        hp.x = (h0 >> 16) | h1;
        hp.y = (h2 >> 16) | h3;
        lp.x = (uint)f2b(v[0] - bitsf(h0)) | ((uint)f2b(v[1] - bitsf(h1)) << 16);
        lp.y = (uint)f2b(v[2] - bitsf(h2)) | ((uint)f2b(v[3] - bitsf(h3)) << 16);
        ushort* o = outb + (size_t)(pf * 16 + ll) * 64 + m * 16 + hl * 4;
        *(uint2*)o = hp;
        *(uint2*)(o + 32) = lp;
      }
  }

  __syncthreads();
#pragma unroll
  for (int m = 0; m < 2; ++m)
#pragma unroll
    for (int pf = 0; pf < 2; ++pf)
#pragma unroll
      for (int i = 0; i < 4; ++i)
        gt[wv][m * 16 + hl * 4 + i][pf * 16 + ll] = acc[2][m][pf][i];
  __syncthreads();
#pragma unroll
  for (int rr = 0; rr < 8; ++rr) {
    int r = rr * 4 + hl, p2 = ll * 2;
    float a = gt[wv][r][p2], bv = gt[wv][r][p2 + 1];
    const float2 pd = *(const float2*)&posdec[(size_t)r * HW + px0 + p2];
    uint pk = (uint)f2b(a + pd.x) | ((uint)f2b(bv + pd.y) << 16);
    *(uint*)(g + ((size_t)b * RCH + r) * HW + px0 + p2) = pk;
  }
}

// ---------------- K2: flash attention, 64-m chunks, low reg pressure ---------
// grid (32, 64), 256 thr = 4 waves; 32 n rows; wave owns m in [wv*256,+256)
__global__ __launch_bounds__(256) void k_attn(const ushort* __restrict__ phiT,
    const ushort* __restrict__ thT, const ushort* __restrict__ g,
    const uint2* __restrict__ posq, float* __restrict__ y2) {
  __shared__ __align__(16) ushort slabm[4][32][72];
  __shared__ float msm[4][32], mss[4][32];
  auto ypw = (float(*)[32][36])slabm;

  const int t = threadIdx.x;
  const int wv = t >> 6, lane = t & 63;
  const int ll = lane & 15, hl = lane >> 4;
  const int b = blockIdx.y;
  const int n0 = blockIdx.x * 32;
  const f32x4 fz = {0.f, 0.f, 0.f, 0.f};

  const ushort* phib = phiT + (size_t)b * (HW * 64);
  const ushort* thb  = thT  + (size_t)b * (HW * 64);
  const ushort* gb   = g    + (size_t)b * (RCH * HW);

  short8 th_h[2], th_l[2];
#pragma unroll
  for (int nf = 0; nf < 2; ++nf) {
    const ushort* ap = &thb[(size_t)(n0 + nf * 16 + ll) * 64 + hl * 8];
    th_h[nf] = *(const short8*)ap;
    th_l[nf] = *(const short8*)(ap + 32);
  }

  f32x4 y[2][2] = {{fz, fz}, {fz, fz}};
  float m_run[2] = {-3e38f, -3e38f};
  float s_run[2] = {0.f, 0.f};

  for (int ck = 0; ck < 4; ++ck) {
    const int mch = wv * 256 + ck * 64;

    // ---- S^T = phi^T @ theta: lane: m = mch + mf*16+hl*4+i, n = nf*16+ll ----
    f32x4 acc[4][2];
#pragma unroll
    for (int mf = 0; mf < 4; ++mf) {
      const ushort* ap = &phib[(size_t)(mch + mf * 16 + ll) * 64 + hl * 8];
      short8 ph = *(const short8*)ap;
      short8 pl = *(const short8*)(ap + 32);
#pragma unroll
      for (int nf = 0; nf < 2; ++nf) {
        f32x4 a = __builtin_amdgcn_mfma_f32_16x16x32_bf16(pl, th_h[nf], fz, 0, 0, 0);
        a = __builtin_amdgcn_mfma_f32_16x16x32_bf16(ph, th_l[nf], a, 0, 0, 0);
        a = __builtin_amdgcn_mfma_f32_16x16x32_bf16(ph, th_h[nf], a, 0, 0, 0);
        acc[mf][nf] = a;
      }
    }

    // ---- + pos from posq[m4][n] (n = ll-consecutive -> coalesced) ----
#pragma unroll
    for (int nf = 0; nf < 2; ++nf) {
      const int nidx = n0 + nf * 16 + ll;
#pragma unroll
      for (int mf = 0; mf < 4; ++mf) {
        uint2 pp = posq[(size_t)((mch >> 2) + mf * 4 + hl) * HW + nidx];
        acc[mf][nf][0] += bitsf(pp.x << 16);
        acc[mf][nf][1] += bitsf(pp.x & 0xffff0000u);
        acc[mf][nf][2] += bitsf(pp.y << 16);
        acc[mf][nf][3] += bitsf(pp.y & 0xffff0000u);
      }
    }

    // ---- online softmax over 64-m chunk (row n = nf*16+ll, reduce over hl) --
#pragma unroll
    for (int nf = 0; nf < 2; ++nf) {
      float mv = acc[0][nf][0];
#pragma unroll
      for (int mf = 0; mf < 4; ++mf)
#pragma unroll
        for (int i = 0; i < 4; ++i) mv = fmaxf(mv, acc[mf][nf][i]);
      mv = fmaxf(mv, __shfl_xor(mv, 16));
      mv = fmaxf(mv, __shfl_xor(mv, 32));
      float mnew = fmaxf(m_run[nf], mv);
      float fac = __expf(m_run[nf] - mnew);
      m_run[nf] = mnew;
      float s_ = 0.f;
#pragma unroll
      for (int mf = 0; mf < 4; ++mf)
#pragma unroll
        for (int i = 0; i < 4; ++i) {
          float p = __expf(acc[mf][nf][i] - mnew);
          acc[mf][nf][i] = p;
          s_ += p;
        }
      s_ += __shfl_xor(s_, 16);
      s_ += __shfl_xor(s_, 32);
      s_run[nf] = s_run[nf] * fac + s_;
#pragma unroll
      for (int rf = 0; rf < 2; ++rf) y[rf][nf] *= fac;
    }

    // ---- PV through per-wave slab (32n x 64m) ----
#pragma unroll
    for (int mf2 = 0; mf2 < 4; ++mf2)
#pragma unroll
      for (int nf = 0; nf < 2; ++nf) {
        f32x4 v = acc[mf2][nf];
        uint2 w;
        w.x = (uint)f2b(v[0]) | ((uint)f2b(v[1]) << 16);
        w.y = (uint)f2b(v[2]) | ((uint)f2b(v[3]) << 16);
        *(uint2*)&slabm[wv][nf * 16 + ll][mf2 * 16 + hl * 4] = w;
      }
    asm volatile("s_waitcnt lgkmcnt(0)" ::: "memory");
    __builtin_amdgcn_sched_barrier(0);
#pragma unroll
    for (int ks = 0; ks < 2; ++ks) {
      short8 bfr[2];
#pragma unroll
      for (int nblk = 0; nblk < 2; ++nblk)
        bfr[nblk] = *(const short8*)&slabm[wv][nblk * 16 + ll][ks * 32 + hl * 8];
#pragma unroll
      for (int rf = 0; rf < 2; ++rf) {
        short8 ag = *(const short8*)&gb[(size_t)(rf * 16 + ll) * HW + mch + ks * 32 + hl * 8];
#pragma unroll
        for (int nblk = 0; nblk < 2; ++nblk)
          y[rf][nblk] = __builtin_amdgcn_mfma_f32_16x16x32_bf16(ag, bfr[nblk], y[rf][nblk], 0, 0, 0);
      }
    }
    asm volatile("s_waitcnt lgkmcnt(0)" ::: "memory");
    __builtin_amdgcn_sched_barrier(0);
  }

  __syncthreads();
#pragma unroll
  for (int rf = 0; rf < 2; ++rf)
#pragma unroll
    for (int nblk = 0; nblk < 2; ++nblk)
      *(f32x4*)&ypw[wv][nblk * 16 + ll][rf * 16 + hl * 4] = y[rf][nblk];
  if (hl == 0) {
    msm[wv][ll] = m_run[0];
    mss[wv][ll] = s_run[0];
    msm[wv][16 + ll] = m_run[1];
    mss[wv][16 + ll] = s_run[1];
  }
  __syncthreads();

  {
    const int n = t & 31, rr = t >> 5;
    float M = msm[0][n];
#pragma unroll
    for (int w = 1; w < 4; ++w) M = fmaxf(M, msm[w][n]);
    float sc[4];
    float s = 0.f;
#pragma unroll
    for (int w = 0; w < 4; ++w) {
      sc[w] = __expf(msm[w][n] - M);
      s += mss[w][n] * sc[w];
    }
    float inv = 1.f / s;
    f32x4 a = sc[0] * (*(const f32x4*)&ypw[0][n][rr * 4]);
#pragma unroll
    for (int w = 1; w < 4; ++w) a += sc[w] * (*(const f32x4*)&ypw[w][n][rr * 4]);
#pragma unroll
    for (int k = 0; k < 4; ++k)
      y2[((size_t)b * RCH + rr * 4 + k) * HW + n0 + n] = a[k] * inv;
  }
}

// ---------------- K3: out = x + Wcomb @ y2 (co split over grid.y) ------------
__global__ __launch_bounds__(256) void k_restore(const float* __restrict__ x,
    const float* __restrict__ Wcomb, const float* __restrict__ y2,
    float* __restrict__ out) {
  const int t = threadIdx.x;
  const int gp = blockIdx.x * 256 + t;
  const int b = gp >> 10, n = gp & 1023;
  const int co0 = blockIdx.y * 64;

  float yv[RCH];
  const float* y2b = y2 + ((size_t)b * RCH) * HW + n;
#pragma unroll
  for (int r = 0; r < RCH; ++r) yv[r] = y2b[(size_t)r * HW];

  const float* xb = x + ((size_t)b * CCH) * HW + n;
  float* ob = out + ((size_t)b * CCH) * HW + n;
  for (int co = co0; co < co0 + 64; ++co) {
    float a = xb[(size_t)co * HW];
#pragma unroll
    for (int qq = 0; qq < RCH; qq += 4) {
      const float4 w = *(const float4*)(Wcomb + co * RCH + qq);
      a += w.x * yv[qq] + w.y * yv[qq + 1] + w.z * yv[qq + 2] + w.w * yv[qq + 3];
    }
    ob[(size_t)co * HW] = a;
  }
}

extern "C" void kernel_launch(void* const* d_in, const int* in_sizes, int n_in,
                              void* d_out, int out_size, void* d_ws, size_t ws_size,
                              hipStream_t stream) {
  const float* x      = (const float*)d_in[0];
  const float* Wred   = (const float*)d_in[1];
  const float* Wrest  = (const float*)d_in[2];
  const float* Wphi   = (const float*)d_in[3];
  const float* Wth    = (const float*)d_in[4];
  const float* Wg     = (const float*)d_in[5];
  const float* Wmask  = (const float*)d_in[6];
  const float* pos    = (const float*)d_in[7];
  const float* posdec = (const float*)d_in[8];
  float* out = (float*)d_out;

  const size_t PT = (size_t)BATCH * HW * 64;     // phiT/thT shorts (hi+lo)
  const size_t NE = (size_t)BATCH * RCH * HW;    // 2M
  ushort* phiT = (ushort*)d_ws;
  ushort* thT  = phiT + PT;
  ushort* gbuf = thT + PT;
  float*  y2   = (float*)(gbuf + NE);
  float*  Wcomb = y2 + NE;
  ushort* Wh   = (ushort*)(Wcomb + CCH * RCH);
  ushort* Wl   = Wh + 3 * RCH * CCH;
  uint2*  posq = (uint2*)(Wl + 3 * RCH * CCH);   // 256K uint2 (2 MB)

  k_prep   <<<dim3(512),     dim3(256), 0, stream>>>(Wred, Wrest, Wphi, Wth, Wg, Wmask,
                                                     pos, Wcomb, Wh, Wl, posq);
  k_qkg    <<<dim3(8, 64),   dim3(256), 0, stream>>>(x, Wh, Wl, posdec, phiT, thT, gbuf);
  k_attn   <<<dim3(32, 64),  dim3(256), 0, stream>>>(phiT, thT, gbuf, posq, y2);
  k_restore<<<dim3(256, 8),  dim3(256), 0, stream>>>(x, Wcomb, y2, out);
}

// Round 9
// 137.876 us; speedup vs baseline: 1.8828x; 1.4697x over previous
//
#include <hip/hip_runtime.h>
#include <cstddef>

#define BATCH 64
#define CCH   512
#define RCH   32
#define HW    1024

typedef __attribute__((ext_vector_type(8))) _Float16 half8;
typedef __attribute__((ext_vector_type(4))) _Float16 half4v;
typedef __attribute__((ext_vector_type(4))) float f32x4;

__device__ inline uint pk2h(float a, float b) {      // 2×f32 -> packed fp16
  auto h = __builtin_amdgcn_cvt_pkrtz(a, b);         // __fp16 ext_vector(2)
  return __builtin_bit_cast(uint, h);
}
__device__ inline ushort h16(float f) {
  _Float16 h = (_Float16)f;
  return __builtin_bit_cast(ushort, h);
}

__device__ inline void gload16(const float* g, float* lds) {
  __builtin_amdgcn_global_load_lds((const __attribute__((address_space(1))) void*)g,
                                   (__attribute__((address_space(3))) void*)lds, 16, 0, 0);
}

// ---------------- K0: weight prep + pos repack -------------------------------
// blk<256: job0 Wcomb = Wrest@Wmask (fp32); job1..3 Wc[mix]=Wmix@Wred -> fp16,
//          packed in MFMA-frag order: [kk][mix][m][lane][8]
// blk 256..511: pos fp32 [n][m] -> posq fp16 [m4][n] (uint2 = 4 consecutive m)
__global__ __launch_bounds__(256) void k_prep(const float* __restrict__ Wred,
    const float* __restrict__ Wrest, const float* __restrict__ Wphi,
    const float* __restrict__ Wth,   const float* __restrict__ Wg,
    const float* __restrict__ Wmask, const float* __restrict__ pos,
    float* __restrict__ Wcomb, _Float16* __restrict__ Whf,
    uint2* __restrict__ posq) {
  const int blk = blockIdx.x;
  const int t = threadIdx.x;
  if (blk >= 256) {
    __shared__ ushort tile[64][68];
    int tb = blk - 256;
    int n0 = (tb >> 4) * 64, m0 = (tb & 15) * 64;
    int nl = t >> 2, c4 = t & 3;
    const float* src = &pos[(size_t)(n0 + nl) * HW + m0 + c4 * 16];
#pragma unroll
    for (int k = 0; k < 4; ++k) {
      float4 p = *(const float4*)(src + k * 4);
      ushort* d = &tile[nl][c4 * 16 + k * 4];
      d[0] = h16(p.x); d[1] = h16(p.y); d[2] = h16(p.z); d[3] = h16(p.w);
    }
    __syncthreads();
    int nl2 = t & 63, mq = t >> 6;
#pragma unroll
    for (int k = 0; k < 4; ++k) {
      int m4l = k * 4 + mq;
      const ushort* s = &tile[nl2][m4l * 4];
      uint2 o;
      o.x = (uint)s[0] | ((uint)s[1] << 16);
      o.y = (uint)s[2] | ((uint)s[3] << 16);
      posq[(size_t)(m0 / 4 + m4l) * HW + n0 + nl2] = o;
    }
    return;
  }
  int tid = blk * 256 + t;
  int job = tid >> 14, idx = tid & 16383;
  if (job == 0) {
    int co = idx >> 5, r = idx & 31;
    float a = 0.f;
#pragma unroll
    for (int rp = 0; rp < RCH; ++rp)
      a += Wrest[co * RCH + rp] * Wmask[rp * RCH + r];
    Wcomb[idx] = a;
  } else {
    const float* Wm = (job == 1) ? Wphi : (job == 2) ? Wth : Wg;
    int rp = idx >> 9, c = idx & 511;
    float a = 0.f;
#pragma unroll
    for (int r = 0; r < RCH; ++r)
      a += Wm[rp * RCH + r] * Wred[r * CCH + c];
    // frag-order pack: kk=c>>5, hl=(c>>3)&3, j=c&7; mix=job-1, m=rp>>4, ll=rp&15
    int kk = c >> 5, hl = (c >> 3) & 3, j = c & 7;
    int mix = job - 1, m = rp >> 4, ll = rp & 15;
    size_t off = ((((size_t)kk * 3 + mix) * 2 + m) * 64 + hl * 16 + ll) * 8 + j;
    Whf[off] = (_Float16)a;
  }
}

// ---------------- K1: phi/theta/g = Wc @ x (fp16 MFMA, LDS-staged x) ---------
// grid (16, 64), 256 thr = 4 waves, 16 px per wave, 64 px per block
__global__ __launch_bounds__(256) void k_qkg(const float* __restrict__ x,
    const _Float16* __restrict__ Whf, const float* __restrict__ posdec,
    _Float16* __restrict__ phiT, _Float16* __restrict__ thT,
    _Float16* __restrict__ g) {
  __shared__ float buf[2][32][64];       // 16 KB double-buffered x tile
  __shared__ float gt[4][32][17];        // 8.7 KB g transpose

  const int t = threadIdx.x;
  const int wv = t >> 6, lane = t & 63;
  const int ll = lane & 15, hl = lane >> 4;
  const int b = blockIdx.y;
  const int px0b = blockIdx.x * 64;
  const f32x4 fz = {0.f, 0.f, 0.f, 0.f};

  f32x4 acc[3][2];
#pragma unroll
  for (int m1 = 0; m1 < 3; ++m1)
#pragma unroll
    for (int m2 = 0; m2 < 2; ++m2) acc[m1][m2] = fz;

  // stage kk=0: 2 rounds x (4 waves x 64 lanes x 16B) = 8 KB
  {
    const float* xbase = x + ((size_t)b * CCH) * HW + px0b;
#pragma unroll
    for (int rd = 0; rd < 2; ++rd) {
      int ch = rd * 16 + wv * 4 + (lane >> 4);
      gload16(xbase + (size_t)ch * HW + (lane & 15) * 4, &buf[0][rd * 16 + wv * 4][0]);
    }
  }
  __syncthreads();

  for (int kk = 0; kk < 16; ++kk) {
    const int cur = kk & 1;
    if (kk < 15) {
      const float* xbase = x + ((size_t)b * CCH + (kk + 1) * 32) * HW + px0b;
#pragma unroll
      for (int rd = 0; rd < 2; ++rd) {
        int ch = rd * 16 + wv * 4 + (lane >> 4);
        gload16(xbase + (size_t)ch * HW + (lane & 15) * 4, &buf[cur ^ 1][rd * 16 + wv * 4][0]);
      }
    }
    float xv[8];
#pragma unroll
    for (int j = 0; j < 8; ++j) xv[j] = buf[cur][hl * 8 + j][wv * 16 + ll];
    union { half8 h8; uint u[4]; } X;
    X.u[0] = pk2h(xv[0], xv[1]);
    X.u[1] = pk2h(xv[2], xv[3]);
    X.u[2] = pk2h(xv[4], xv[5]);
    X.u[3] = pk2h(xv[6], xv[7]);
#pragma unroll
    for (int mix = 0; mix < 3; ++mix)
#pragma unroll
      for (int m = 0; m < 2; ++m) {
        half8 wh = *(const half8*)&Whf[((((size_t)kk * 3 + mix) * 2 + m) * 64 + lane) * 8];
        acc[mix][m] = __builtin_amdgcn_mfma_f32_16x16x32_f16(wh, X.h8, acc[mix][m], 0, 0, 0);
      }
    __syncthreads();
  }

  // phi/theta: [b][px][32] fp16
#pragma unroll
  for (int mix = 0; mix < 2; ++mix) {
    _Float16* outb = (mix ? thT : phiT) + ((size_t)b * HW + px0b + wv * 16) * 32;
#pragma unroll
    for (int m = 0; m < 2; ++m) {
      f32x4 v = acc[mix][m];
      uint2 o;
      o.x = pk2h(v[0], v[1]);
      o.y = pk2h(v[2], v[3]);
      *(uint2*)(outb + (size_t)ll * 32 + m * 16 + hl * 4) = o;
    }
  }

  // g: [b][r][px] fp16 via LDS transpose, +posdec
  __syncthreads();
#pragma unroll
  for (int m = 0; m < 2; ++m)
#pragma unroll
    for (int i = 0; i < 4; ++i)
      gt[wv][m * 16 + hl * 4 + i][ll] = acc[2][m][i];
  __syncthreads();
#pragma unroll
  for (int rr = 0; rr < 4; ++rr) {
    int r = rr * 8 + hl * 2 + (ll >> 3), p2 = (ll & 7) * 2;
    const float2 pd = *(const float2*)&posdec[(size_t)r * HW + px0b + wv * 16 + p2];
    uint pk = pk2h(gt[wv][r][p2] + pd.x, gt[wv][r][p2 + 1] + pd.y);
    *(uint*)&g[((size_t)b * RCH + r) * HW + px0b + wv * 16 + p2] = pk;
  }
}

// ---------------- K2: flash attention, fp16, per-wave-complete ---------------
// grid (8, 64), 512 thr = 8 waves; wave owns 16 n rows over ALL 1024 m.
// No cross-wave merge, no __syncthreads.
__global__ __launch_bounds__(512) void k_attn(const _Float16* __restrict__ phiT,
    const _Float16* __restrict__ thT, const _Float16* __restrict__ g,
    const _Float16* __restrict__ posqh, float* __restrict__ y2) {
  __shared__ __align__(16) _Float16 slabm[8][16][72];   // 18.4 KB P slabs

  const int t = threadIdx.x;
  const int wv = t >> 6, lane = t & 63;
  const int ll = lane & 15, hl = lane >> 4;
  const int b = blockIdx.y;
  const int nw = blockIdx.x * 128 + wv * 16;            // wave's 16 n-rows
  const f32x4 fz = {0.f, 0.f, 0.f, 0.f};

  const _Float16* phib = phiT + (size_t)b * (HW * 32);
  const _Float16* thb  = thT  + (size_t)b * (HW * 32);
  const _Float16* gb   = g    + (size_t)b * (RCH * HW);

  // theta B-frag (persistent): col=ll -> n, k=hl*8+j -> channel
  half8 th = *(const half8*)&thb[(size_t)(nw + ll) * 32 + hl * 8];

  f32x4 y[2] = {fz, fz};                 // col=ll -> n, row=hl*4+i -> r
  float m_run = -3e38f, s_run = 0.f;

  for (int ck = 0; ck < 8; ++ck) {
    const int mch = ck * 128;

    // ---- S^T = phi^T @ theta: lane: m = mf*16+hl*4+i, n = ll ----
    f32x4 acc[8];
#pragma unroll
    for (int mf = 0; mf < 8; ++mf) {
      half8 ph = *(const half8*)&phib[(size_t)(mch + mf * 16 + ll) * 32 + hl * 8];
      acc[mf] = __builtin_amdgcn_mfma_f32_16x16x32_f16(ph, th, fz, 0, 0, 0);
    }

    // ---- + pos from posq[m4][n] fp16 (n = ll-consecutive -> coalesced) ----
#pragma unroll
    for (int mf = 0; mf < 8; ++mf) {
      half4v pp = *(const half4v*)&posqh[((size_t)(ck * 32 + mf * 4 + hl) * HW + nw + ll) * 4];
#pragma unroll
      for (int i = 0; i < 4; ++i) acc[mf][i] += (float)pp[i];
    }

    // ---- online softmax over 128-m chunk (row n = ll, reduce over hl) ----
    float mv = acc[0][0];
#pragma unroll
    for (int mf = 0; mf < 8; ++mf)
#pragma unroll
      for (int i = 0; i < 4; ++i) mv = fmaxf(mv, acc[mf][i]);
    mv = fmaxf(mv, __shfl_xor(mv, 16));
    mv = fmaxf(mv, __shfl_xor(mv, 32));
    float mnew = fmaxf(m_run, mv);
    float fac = __expf(m_run - mnew);
    m_run = mnew;
    float s_ = 0.f;
#pragma unroll
    for (int mf = 0; mf < 8; ++mf)
#pragma unroll
      for (int i = 0; i < 4; ++i) {
        float p = __expf(acc[mf][i] - mnew);
        acc[mf][i] = p;
        s_ += p;
      }
    s_ += __shfl_xor(s_, 16);
    s_ += __shfl_xor(s_, 32);
    s_run = s_run * fac + s_;
    y[0] *= fac;
    y[1] *= fac;

    // ---- PV in two 64-m halves through per-wave slab ----
#pragma unroll
    for (int h = 0; h < 2; ++h) {
#pragma unroll
      for (int mf2 = 0; mf2 < 4; ++mf2) {
        f32x4 v = acc[h * 4 + mf2];
        uint2 w;
        w.x = pk2h(v[0], v[1]);
        w.y = pk2h(v[2], v[3]);
        *(uint2*)&slabm[wv][ll][mf2 * 16 + hl * 4] = w;
      }
      asm volatile("s_waitcnt lgkmcnt(0)" ::: "memory");
      __builtin_amdgcn_sched_barrier(0);
#pragma unroll
      for (int ks = 0; ks < 2; ++ks) {
        half8 bfr = *(const half8*)&slabm[wv][ll][ks * 32 + hl * 8];
#pragma unroll
        for (int rf = 0; rf < 2; ++rf) {
          half8 ag = *(const half8*)&gb[(size_t)(rf * 16 + ll) * HW + mch + h * 64 + ks * 32 + hl * 8];
          y[rf] = __builtin_amdgcn_mfma_f32_16x16x32_f16(ag, bfr, y[rf], 0, 0, 0);
        }
      }
      asm volatile("s_waitcnt lgkmcnt(0)" ::: "memory");
      __builtin_amdgcn_sched_barrier(0);
    }
  }

  // ---- normalize + store (per-wave complete) ----
  float inv = 1.f / s_run;
#pragma unroll
  for (int rf = 0; rf < 2; ++rf)
#pragma unroll
    for (int i = 0; i < 4; ++i)
      y2[((size_t)b * RCH + rf * 16 + hl * 4 + i) * HW + nw + ll] = y[rf][i] * inv;
}

// ---------------- K3: out = x + Wcomb @ y2 (co split over grid.y) ------------
__global__ __launch_bounds__(256) void k_restore(const float* __restrict__ x,
    const float* __restrict__ Wcomb, const float* __restrict__ y2,
    float* __restrict__ out) {
  const int t = threadIdx.x;
  const int gp = blockIdx.x * 256 + t;
  const int b = gp >> 10, n = gp & 1023;
  const int co0 = blockIdx.y * 64;

  float yv[RCH];
  const float* y2b = y2 + ((size_t)b * RCH) * HW + n;
#pragma unroll
  for (int r = 0; r < RCH; ++r) yv[r] = y2b[(size_t)r * HW];

  const float* xb = x + ((size_t)b * CCH) * HW + n;
  float* ob = out + ((size_t)b * CCH) * HW + n;
  for (int co = co0; co < co0 + 64; ++co) {
    float a = xb[(size_t)co * HW];
#pragma unroll
    for (int qq = 0; qq < RCH; qq += 4) {
      const float4 w = *(const float4*)(Wcomb + co * RCH + qq);
      a += w.x * yv[qq] + w.y * yv[qq + 1] + w.z * yv[qq + 2] + w.w * yv[qq + 3];
    }
    ob[(size_t)co * HW] = a;
  }
}

extern "C" void kernel_launch(void* const* d_in, const int* in_sizes, int n_in,
                              void* d_out, int out_size, void* d_ws, size_t ws_size,
                              hipStream_t stream) {
  const float* x      = (const float*)d_in[0];
  const float* Wred   = (const float*)d_in[1];
  const float* Wrest  = (const float*)d_in[2];
  const float* Wphi   = (const float*)d_in[3];
  const float* Wth    = (const float*)d_in[4];
  const float* Wg     = (const float*)d_in[5];
  const float* Wmask  = (const float*)d_in[6];
  const float* pos    = (const float*)d_in[7];
  const float* posdec = (const float*)d_in[8];
  float* out = (float*)d_out;

  const size_t NE = (size_t)BATCH * RCH * HW;      // 2M elements
  _Float16* phiT = (_Float16*)d_ws;                // 4 MB
  _Float16* thT  = phiT + NE;                      // 4 MB
  _Float16* gbuf = thT + NE;                       // 4 MB
  float*    y2   = (float*)(gbuf + NE);            // 8 MB
  float*    Wcomb = y2 + NE;                       // 64 KB
  _Float16* Whf  = (_Float16*)(Wcomb + CCH * RCH); // 96 KB
  _Float16* posqh = Whf + 3 * RCH * CCH;           // 2 MB, 16B-aligned

  k_prep   <<<dim3(512),     dim3(256), 0, stream>>>(Wred, Wrest, Wphi, Wth, Wg, Wmask,
                                                     pos, Wcomb, Whf, (uint2*)posqh);
  k_qkg    <<<dim3(16, 64),  dim3(256), 0, stream>>>(x, Whf, posdec, phiT, thT, gbuf);
  k_attn   <<<dim3(8, 64),   dim3(512), 0, stream>>>(phiT, thT, gbuf, posqh, y2);
  k_restore<<<dim3(256, 8),  dim3(256), 0, stream>>>(x, Wcomb, y2, out);
}